// Round 9
// baseline (404.942 us; speedup 1.0000x reference)
//
#include <hip/hip_runtime.h>
#include <hip/hip_fp16.h>

#define BLOCK 256
#define PAD 16        // one counter per 64B cache line
#define SCAP 4096     // unified staging capacity per bucket (records)
#define OVCAP 4096    // overflow capacity per bucket
#define BUFCAP 4352   // binB LDS record capacity

// binA LDS binning
#define NBIN 416          // >= NBUK (=391 for N=50000)
#define CAPBIG 16         // per-bin LDS capacity (records)
#define BINA_THREADS 1024
#define BINA_BLOCKS 256

typedef _Float16 h2v __attribute__((ext_vector_type(2)));

#if defined(__has_builtin) && __has_builtin(__builtin_amdgcn_sched_barrier)
#define SCHED_FENCE() __builtin_amdgcn_sched_barrier(0)
#else
#define SCHED_FENCE()
#endif

// ---------------- helpers ----------------
__device__ inline void st4f(__half* p, float4 v) {
    __half2 a = __floats2half2_rn(v.x, v.y);
    __half2 b = __floats2half2_rn(v.z, v.w);
    uint2 u;
    u.x = *reinterpret_cast<unsigned*>(&a);
    u.y = *reinterpret_cast<unsigned*>(&b);
    *(uint2*)p = u;
}
__device__ inline void st4f(float* p, float4 v) { *(float4*)p = v; }
__device__ inline void st8f(float* p, const float f[8]) {
    *(float4*)p       = make_float4(f[0], f[1], f[2], f[3]);
    *(float4*)(p + 4) = make_float4(f[4], f[5], f[6], f[7]);
}
__device__ inline void st8f(__half* p, const float f[8]) {
    union { __half2 h[4]; float4 v; } u;
    u.h[0] = __floats2half2_rn(f[0], f[1]);
    u.h[1] = __floats2half2_rn(f[2], f[3]);
    u.h[2] = __floats2half2_rn(f[4], f[5]);
    u.h[3] = __floats2half2_rn(f[6], f[7]);
    *(float4*)p = u.v;
}
__device__ inline void ld2v(const __half* p, float* f) {
    float2 v = __half22float2(*(const __half2*)p); f[0] = v.x; f[1] = v.y;
}
__device__ inline void ld4v(const __half* p, float* f) {
    float2 r = *(const float2*)p;   // 8B = 4 halves
    const __half2* h = (const __half2*)&r;
    float2 a = __half22float2(h[0]), b = __half22float2(h[1]);
    f[0] = a.x; f[1] = a.y; f[2] = b.x; f[3] = b.y;
}
__device__ inline void ld8v(const __half* p, float* f) {
    float4 r = *(const float4*)p;
    const __half2* h = (const __half2*)&r;
#pragma unroll
    for (int j = 0; j < 4; ++j) {
        float2 fj = __half22float2(h[j]);
        f[2*j] = fj.x; f[2*j+1] = fj.y;
    }
}
__device__ inline float4 ld4f(const float* p) { return *(const float4*)p; }
__device__ inline float edgeW(int2 er) {
    return __half2float(__ushort_as_half((unsigned short)(er.y & 0xffff)));
}
__device__ inline h2v packh2(float a, float b) {
    h2v r; r.x = (_Float16)a; r.y = (_Float16)b; return r;
}
// non-temporal 8B record load (int2 via long long bit-cast)
__device__ inline int2 ntld2(const int2* p) {
    long long v = __builtin_nontemporal_load((const long long*)p);
    union { long long l; int2 i; } u; u.l = v; return u.i;
}

// ---------------- binA: LDS-binned edge staging, full-line flushes ----------------
__global__ __launch_bounds__(BINA_THREADS) void binA_kernel(
    const int* __restrict__ src, const int* __restrict__ dst,
    const float* __restrict__ efet,
    int* __restrict__ degO_x,
    int* __restrict__ scur, int* __restrict__ ovcur,
    int2* __restrict__ staging, int2* __restrict__ overflow,
    int N, int E, int NBUK) {
    __shared__ int2 bins[NBIN][CAPBIG];
    __shared__ int  lcnt[NBIN];
    const int t = threadIdx.x;
    for (int b = t; b < NBIN; b += BINA_THREADS) lcnt[b] = 0;
    __syncthreads();

    const int nbuk_c = (NBUK < NBIN) ? NBUK : NBIN;
    const int chunk = (E + gridDim.x - 1) / gridDim.x;
    const int e0 = blockIdx.x * chunk;
    int e1 = e0 + chunk; if (e1 > E) e1 = E;
    const int xcc = __builtin_amdgcn_s_getreg(63508) & 7;   // hwreg(XCC_ID)

    for (int base = e0; base < e1; base += BINA_THREADS) {
        const int e = base + t;
        if (e < e1) {
            int s = __builtin_nontemporal_load(src + e);
            int d = __builtin_nontemporal_load(dst + e);
            float w = __builtin_nontemporal_load(efet + e);
            atomicAdd(&degO_x[(size_t)xcc * N + s], 1);     // XCD-local, fire & forget
            int b = d >> 7;
            int2 rec;
            rec.x = s;
            rec.y = (int)__half_as_ushort(__float2half(w)) | ((d & 127) << 16);
            int pos = (b < NBIN) ? atomicAdd(&lcnt[b], 1) : CAPBIG;
            if (pos < CAPBIG) {
                bins[b][pos] = rec;
            } else {
                int q = atomicAdd(&ovcur[b * PAD], 1);
                if (q < OVCAP) overflow[(size_t)b * OVCAP + q] = rec;
            }
        }
        __syncthreads();
        // flush full groups of 8 records (64B-aligned line writes)
        for (int b = t; b < nbuk_c; b += BINA_THREADS) {
            int c = lcnt[b];
            if (c > CAPBIG) c = CAPBIG;
            int nf = c & ~7;
            if (nf) {
                int g = atomicAdd(&scur[b * PAD], nf);
                if (g + nf <= SCAP) {
                    const int4* s4 = (const int4*)&bins[b][0];
                    int4* d4 = (int4*)(staging + (size_t)b * SCAP + g);
                    for (int i = 0; i < (nf >> 1); ++i) d4[i] = s4[i];
                } else {
                    for (int i = 0; i < nf; ++i) {
                        int gg = g + i;
                        if (gg < SCAP) staging[(size_t)b * SCAP + gg] = bins[b][i];
                        else {
                            int q = atomicAdd(&ovcur[b * PAD], 1);
                            if (q < OVCAP) overflow[(size_t)b * OVCAP + q] = bins[b][i];
                        }
                    }
                }
                int rem = c - nf;
                for (int i = 0; i < rem; ++i) bins[b][i] = bins[b][nf + i];
                lcnt[b] = rem;
            }
        }
        __syncthreads();
    }
    for (int b = t; b < nbuk_c; b += BINA_THREADS) {
        int c = lcnt[b];
        if (c > CAPBIG) c = CAPBIG;
        if (c > 0) {
            int q = atomicAdd(&ovcur[b * PAD], c);
            for (int i = 0; i < c; ++i)
                if (q + i < OVCAP) overflow[(size_t)b * OVCAP + q + i] = bins[b][i];
        }
    }
}

// ---------------- binB: bucket drain -> rowSpan + edges + norms + xh ----------------
__global__ __launch_bounds__(256) void binB_kernel(
    const int* __restrict__ scur, const int* __restrict__ ovcur,
    const int2* __restrict__ staging, const int2* __restrict__ overflow,
    int* __restrict__ gcur, int2* __restrict__ rowSpan, float* __restrict__ normI,
    int2* __restrict__ edges,
    const int* __restrict__ degO_x, const float* __restrict__ x,
    __half* __restrict__ xh, float* __restrict__ normO, int N) {
    __shared__ int2 buf[BUFCAP];
    __shared__ int cnt[128];
    __shared__ int rs[128];
    __shared__ int cur[128];
    __shared__ float nO[128];
    __shared__ int base;
    int b = blockIdx.x;
    int v0 = b << 7;
    int t = threadIdx.x;
    int nn = N - v0; if (nn > 128) nn = 128;
    if (t < 128) cnt[t] = 0;

    int c = scur[b * PAD];
    if (c > SCAP) c = SCAP;
    int oc = ovcur[b * PAD];
    if (oc > OVCAP) oc = OVCAP;
    int total = c + oc;
    if (total > BUFCAP) total = BUFCAP;
    __syncthreads();

    {
        const int2* reg = staging + (size_t)b * SCAP;
        for (int i = t; i < c; i += 256) {
            if (i < BUFCAP) buf[i] = ntld2(reg + i);
        }
    }
    {
        const int2* reg = overflow + (size_t)b * OVCAP;
        for (int i = t; i < oc; i += 256) {
            int o = c + i;
            if (o < BUFCAP) buf[o] = ntld2(reg + i);
        }
    }
    __syncthreads();

    for (int i = t; i < total; i += 256)
        atomicAdd(&cnt[(buf[i].y >> 16) & 127], 1);
    __syncthreads();

    if (t == 0) {
        base = atomicAdd(gcur, total);
        int a2 = 0;
        for (int k = 0; k < 128; ++k) { rs[k] = a2; a2 += cnt[k]; }
    }
    __syncthreads();

    if (t < 128) {
        cur[t] = 0;
        int v = v0 + t;
        if (v < N) {
            int2 sp;
            sp.x = base + rs[t];
            sp.y = sp.x + cnt[t];
            rowSpan[v] = sp;
            normI[v] = rsqrtf(fmaxf((float)cnt[t], 1.0f));
            int dsum = 0;
#pragma unroll
            for (int k = 0; k < 8; ++k) dsum += degO_x[(size_t)k * N + v];
            float wv = rsqrtf(fmaxf((float)dsum, 1.0f));
            nO[t] = wv;
            normO[v] = wv;
        }
    }
    __syncthreads();

    for (int i = t; i < total; i += 256) {
        int2 rec = buf[i];
        int dl = (rec.y >> 16) & 127;
        int lp = atomicAdd(&cur[dl], 1);
        edges[base + rs[dl] + lp] = rec;
    }

    for (int i = t; i < nn * 4; i += 256) {
        int vl = i >> 2, cc = (i & 3) * 4;
        int v = v0 + vl;
        float4 f = ld4f(x + (size_t)v * 16 + cc);
        float wv = nO[vl];
        f.x *= wv; f.y *= wv; f.z *= wv; f.w *= wv;
        st4f(xh + (size_t)v * 16 + cc, f);
    }
}

// ---------------- CSR gather-agg, 8 cols/thread, LDS-staged edge window ------------
// bias may be null (scale-only epilogue, used by the post-GEMM EWA passes).
template <int D>
__global__ __launch_bounds__(256) void agg8_kernel(
    const __half* __restrict__ in, __half* __restrict__ out,
    const int2* __restrict__ rowSpan, const int2* __restrict__ edges,
    int useW,
    const float* __restrict__ dstScale,   // null -> skip scale+bias
    const float* __restrict__ bias,       // null -> scale only
    int N, int relu) {
    constexpr int TPN = D / 8;
    constexpr int NN  = 256 / TPN;                       // nodes per block
    constexpr int ECAP = (NN * 32 < 2560) ? NN * 32 : 2560;  // >=11 sd over mean NN*16
    __shared__ int2 eb[ECAP];
    __shared__ int s_w[2];
    const int t = threadIdx.x;
    const int v0 = blockIdx.x * NN;
    if (t == 0) {
        int vl = v0 + NN - 1; if (vl >= N) vl = N - 1;
        s_w[0] = rowSpan[v0].x;
        s_w[1] = rowSpan[vl].y;
    }
    __syncthreads();
    const int wbeg = s_w[0];
    int nst = s_w[1] - wbeg; if (nst > ECAP) nst = ECAP;
    for (int i = t; i < nst; i += 256) eb[i] = ntld2(&edges[wbeg + i]);
    __syncthreads();

    int v = v0 + t / TPN;
    int c8 = (t % TPN) * 8;
    if (v >= N) return;
    int2 sp = rowSpan[v];
    int beg = sp.x, end = sp.y;
    float a[8];
#pragma unroll
    for (int k = 0; k < 8; ++k) a[k] = 0.f;
    const __half* base = in + c8;

    auto erec = [&](int j) -> int2 {
        int o = j - wbeg;
        return (o < nst) ? eb[o] : edges[j];
    };

    int j = beg;
    for (; j + 8 <= end; j += 8) {
        int2 er[8];
#pragma unroll
        for (int q = 0; q < 8; ++q) er[q] = erec(j + q);
        SCHED_FENCE();
        float4 raw[8];
#pragma unroll
        for (int q = 0; q < 8; ++q) raw[q] = *(const float4*)(base + (size_t)er[q].x * D);
        SCHED_FENCE();
#pragma unroll
        for (int q = 0; q < 8; ++q) {
            float w = useW ? edgeW(er[q]) : 1.f;
            const __half2* h = (const __half2*)&raw[q];
#pragma unroll
            for (int p = 0; p < 4; ++p) {
                float2 fj = __half22float2(h[p]);
                a[2*p]   += fj.x * w;
                a[2*p+1] += fj.y * w;
            }
        }
    }
    if (j + 4 <= end) {
        int2 er[4];
#pragma unroll
        for (int q = 0; q < 4; ++q) er[q] = erec(j + q);
        SCHED_FENCE();
        float4 raw[4];
#pragma unroll
        for (int q = 0; q < 4; ++q) raw[q] = *(const float4*)(base + (size_t)er[q].x * D);
        SCHED_FENCE();
#pragma unroll
        for (int q = 0; q < 4; ++q) {
            float w = useW ? edgeW(er[q]) : 1.f;
            const __half2* h = (const __half2*)&raw[q];
#pragma unroll
            for (int p = 0; p < 4; ++p) {
                float2 fj = __half22float2(h[p]);
                a[2*p]   += fj.x * w;
                a[2*p+1] += fj.y * w;
            }
        }
        j += 4;
    }
    for (; j < end; ++j) {
        int2 er = erec(j);
        float w = useW ? edgeW(er) : 1.f;
        float xv[8];
        ld8v(base + (size_t)er.x * D, xv);
#pragma unroll
        for (int k = 0; k < 8; ++k) a[k] += xv[k] * w;
    }
    if (dstScale) {
        float sc = dstScale[v];
        if (bias) {
#pragma unroll
            for (int k = 0; k < 8; ++k) a[k] = a[k] * sc + bias[c8 + k];
        } else {
#pragma unroll
            for (int k = 0; k < 8; ++k) a[k] *= sc;
        }
    }
    if (relu) {
#pragma unroll
        for (int k = 0; k < 8; ++k) a[k] = fmaxf(a[k], 0.f);
    }
    st8f(out + (size_t)v * D + c8, a);
}

// ---------------- gc32 fused with 32->4 GEMM (W5), LDS-staged edges ----------------
__global__ __launch_bounds__(256) void gc32_fused(
    const __half* __restrict__ in, float* __restrict__ t5,
    const int2* __restrict__ rowSpan, const int2* __restrict__ edges,
    const float* __restrict__ normI, const float* __restrict__ b4,
    const float* __restrict__ normO, const float* __restrict__ W5,
    int N) {
    constexpr int NN = 64;               // nodes per block (4 threads/node)
    constexpr int ECAP = 2048;
    __shared__ int2 eb[ECAP];
    __shared__ int s_w[2];
    const int t = threadIdx.x;
    const int v0 = blockIdx.x * NN;
    if (t == 0) {
        int vl = v0 + NN - 1; if (vl >= N) vl = N - 1;
        s_w[0] = rowSpan[v0].x;
        s_w[1] = rowSpan[vl].y;
    }
    __syncthreads();
    const int wbeg = s_w[0];
    int nst = s_w[1] - wbeg; if (nst > ECAP) nst = ECAP;
    for (int i = t; i < nst; i += 256) eb[i] = ntld2(&edges[wbeg + i]);
    __syncthreads();

    int v = v0 + (t >> 2);
    int q = t & 3;
    int c8 = q * 8;
    if (v >= N) return;
    int2 sp = rowSpan[v];
    int beg = sp.x, end = sp.y;
    float a[8];
#pragma unroll
    for (int k = 0; k < 8; ++k) a[k] = 0.f;
    const __half* base = in + c8;

    auto erec = [&](int j) -> int2 {
        int o = j - wbeg;
        return (o < nst) ? eb[o] : edges[j];
    };

    int j = beg;
    for (; j + 8 <= end; j += 8) {
        int2 er[8];
#pragma unroll
        for (int p = 0; p < 8; ++p) er[p] = erec(j + p);
        SCHED_FENCE();
        float4 raw[8];
#pragma unroll
        for (int p = 0; p < 8; ++p) raw[p] = *(const float4*)(base + (size_t)er[p].x * 32);
        SCHED_FENCE();
#pragma unroll
        for (int p = 0; p < 8; ++p) {
            const __half2* h = (const __half2*)&raw[p];
#pragma unroll
            for (int s = 0; s < 4; ++s) {
                float2 fj = __half22float2(h[s]);
                a[2*s]   += fj.x;
                a[2*s+1] += fj.y;
            }
        }
    }
    for (; j < end; ++j) {
        int2 er = erec(j);
        float xv[8];
        ld8v(base + (size_t)er.x * 32, xv);
#pragma unroll
        for (int k = 0; k < 8; ++k) a[k] += xv[k];
    }
    float sc = normI[v];
#pragma unroll
    for (int k = 0; k < 8; ++k) a[k] = fmaxf(a[k] * sc + b4[c8 + k], 0.f);

    float p4[4] = {0.f, 0.f, 0.f, 0.f};
#pragma unroll
    for (int k = 0; k < 8; ++k) {
        float4 wr = ld4f(W5 + (size_t)(c8 + k) * 4);
        p4[0] += a[k] * wr.x; p4[1] += a[k] * wr.y;
        p4[2] += a[k] * wr.z; p4[3] += a[k] * wr.w;
    }
#pragma unroll
    for (int c = 0; c < 4; ++c) {
        p4[c] += __shfl_xor(p4[c], 1);
        p4[c] += __shfl_xor(p4[c], 2);
    }
    if (q == 0) {
        float no = normO[v];
        st4f(t5 + (size_t)v * 4, make_float4(p4[0]*no, p4[1]*no, p4[2]*no, p4[3]*no));
    }
}

// ---------------- final agg: D=4, fp32, batched loads ----------------
__global__ void agg4_kernel(const float* __restrict__ in, float* __restrict__ out,
                            const int2* __restrict__ rowSpan, const int2* __restrict__ edges,
                            const float* __restrict__ dstScale, const float* __restrict__ bias,
                            int N) {
    int v = blockIdx.x * blockDim.x + threadIdx.x;
    if (v >= N) return;
    int2 sp = rowSpan[v];
    int beg = sp.x, end = sp.y;
    float ax = 0.f, ay = 0.f, az = 0.f, aw = 0.f;
    int j = beg;
    for (; j + 4 <= end; j += 4) {
        int2 er[4];
#pragma unroll
        for (int q = 0; q < 4; ++q) er[q] = edges[j + q];
        SCHED_FENCE();
        float4 raw[4];
#pragma unroll
        for (int q = 0; q < 4; ++q) raw[q] = ld4f(in + (size_t)er[q].x * 4);
        SCHED_FENCE();
#pragma unroll
        for (int q = 0; q < 4; ++q) {
            ax += raw[q].x; ay += raw[q].y; az += raw[q].z; aw += raw[q].w;
        }
    }
    for (; j < end; ++j) {
        float4 val = ld4f(in + (size_t)edges[j].x * 4);
        ax += val.x; ay += val.y; az += val.z; aw += val.w;
    }
    float sc = dstScale[v];
    ax = ax * sc + bias[0];
    ay = ay * sc + bias[1];
    az = az * sc + bias[2];
    aw = aw * sc + bias[3];
    st4f(out + (size_t)v * 4, make_float4(ax, ay, az, aw));
}

// ---------------- tiled GEMM with v_dot2_f32_f16 ----------------
// Round-9 rework for the LDS-read bottleneck (SQ_LDS_BANK_CONFLICT=3.2M on the
// 256->128 GEMM, VALUBusy 45%):
//  (1) Wlds swizzle phys(c) = c + (c>>5)*4  (16B pad per 128B): the per-wave
//      W-fragment reads (16 chunks at 32B stride -> banks {0,8,16,24}, 4-way;
//      8-way at TN=256) become <=2-way, which is free.
//  (2) RPT doubled (8/4/2 rows per thread): halves LDS bytes per FLOP, flipping
//      the kernel from LDS-pipe-bound to VALU-bound.
template <int KT, int RPT, int TN>
__global__ __launch_bounds__(256) void gemm_tiled(
    const __half* __restrict__ A, const float* __restrict__ W,
    const float* __restrict__ rowScaleIn,   // null -> 1
    const float* __restrict__ rowScaleOut,  // null -> no scale/bias
    const float* __restrict__ bias,
    __half* __restrict__ C, int N, int K1, int relu)
{
    constexpr int NC8 = TN / 8;
    constexpr int RT  = 256 / NC8;
    constexpr int TM  = RT * RPT;
    constexpr int AFPT = TM * KT / 256;
    constexpr int KP  = KT / 2;
    constexpr int WRS = TN + (TN >> 5) * 4;   // swizzled Wlds row stride (h2v units)
    static_assert(AFPT == 2 || AFPT == 4 || AFPT == 8 || AFPT == 16, "unexpected AFPT");
    static_assert(RPT == 1 || RPT == 2 || RPT == 4 || RPT == 8, "unexpected RPT");

    __shared__ h2v Alds[KP][TM];
    __shared__ h2v Wlds[KP][WRS];

    const int t    = threadIdx.x;
    const int cg   = t % NC8;
    const int rt   = t / NC8;
    const int c0   = cg * 8;
    const int row0 = blockIdx.x * TM;
    const int pc0  = c0 + ((c0 >> 5) << 2);   // swizzled read base (c0..c0+7 stay contiguous)

    const int arow   = t % TM;
    const int akb    = (t / TM) * AFPT;
    const int arow_g = row0 + arow;
    float rsc = 1.0f;
    if (rowScaleIn && arow_g < N) rsc = rowScaleIn[arow_g];

    float acc[RPT][8];
#pragma unroll
    for (int r = 0; r < RPT; ++r)
#pragma unroll
        for (int j = 0; j < 8; ++j) acc[r][j] = 0.f;

    for (int k0 = 0; k0 < K1; k0 += KT) {
        float av[AFPT];
        if (arow_g < N) {
            const __half* ag = A + (size_t)arow_g * K1 + k0 + akb;
            if constexpr (AFPT == 16) { ld8v(ag, av); ld8v(ag + 8, av + 8); }
            else if constexpr (AFPT == 8) ld8v(ag, av);
            else if constexpr (AFPT == 4) ld4v(ag, av);
            else                          ld2v(ag, av);
        } else {
#pragma unroll
            for (int j = 0; j < AFPT; ++j) av[j] = 0.f;
        }
#pragma unroll
        for (int j = 0; j < AFPT; j += 2)
            Alds[(akb + j) >> 1][arow] = packh2(av[j] * rsc, av[j + 1] * rsc);

        for (int i = t; i < KP * TN; i += 256) {
            int kp = i / TN, c = i % TN;
            Wlds[kp][c + ((c >> 5) << 2)] = packh2(W[(size_t)(k0 + 2 * kp) * TN + c],
                                                   W[(size_t)(k0 + 2 * kp + 1) * TN + c]);
        }
        __syncthreads();

#pragma unroll
        for (int kp = 0; kp < KP; ++kp) {
            h2v a2[RPT];
            if constexpr (RPT == 8) {
                union { float4 f; h2v h[4]; } u0, u1;
                u0.f = *(const float4*)&Alds[kp][rt * 8];
                u1.f = *(const float4*)&Alds[kp][rt * 8 + 4];
                a2[0] = u0.h[0]; a2[1] = u0.h[1]; a2[2] = u0.h[2]; a2[3] = u0.h[3];
                a2[4] = u1.h[0]; a2[5] = u1.h[1]; a2[6] = u1.h[2]; a2[7] = u1.h[3];
            } else if constexpr (RPT == 4) {
                union { float4 f; h2v h[4]; } u;
                u.f = *(const float4*)&Alds[kp][rt * 4];
                a2[0] = u.h[0]; a2[1] = u.h[1]; a2[2] = u.h[2]; a2[3] = u.h[3];
            } else if constexpr (RPT == 2) {
                union { float2 f; h2v h[2]; } u;
                u.f = *(const float2*)&Alds[kp][rt * 2];
                a2[0] = u.h[0]; a2[1] = u.h[1];
            } else {
                a2[0] = Alds[kp][rt];
            }
            union { float4 f; h2v h[4]; } w0, w1;
            w0.f = *(const float4*)&Wlds[kp][pc0];
            w1.f = *(const float4*)&Wlds[kp][pc0 + 4];
#pragma unroll
            for (int r = 0; r < RPT; ++r) {
                acc[r][0] = __builtin_amdgcn_fdot2(a2[r], w0.h[0], acc[r][0], false);
                acc[r][1] = __builtin_amdgcn_fdot2(a2[r], w0.h[1], acc[r][1], false);
                acc[r][2] = __builtin_amdgcn_fdot2(a2[r], w0.h[2], acc[r][2], false);
                acc[r][3] = __builtin_amdgcn_fdot2(a2[r], w0.h[3], acc[r][3], false);
                acc[r][4] = __builtin_amdgcn_fdot2(a2[r], w1.h[0], acc[r][4], false);
                acc[r][5] = __builtin_amdgcn_fdot2(a2[r], w1.h[1], acc[r][5], false);
                acc[r][6] = __builtin_amdgcn_fdot2(a2[r], w1.h[2], acc[r][6], false);
                acc[r][7] = __builtin_amdgcn_fdot2(a2[r], w1.h[3], acc[r][7], false);
            }
        }
        __syncthreads();
    }

#pragma unroll
    for (int r = 0; r < RPT; ++r) {
        int row_g = row0 + rt * RPT + r;
        if (row_g >= N) continue;
        float f[8];
        if (rowScaleOut) {
            float sc = rowScaleOut[row_g];
#pragma unroll
            for (int j = 0; j < 8; ++j) f[j] = acc[r][j] * sc + bias[c0 + j];
        } else {
#pragma unroll
            for (int j = 0; j < 8; ++j) f[j] = acc[r][j];
        }
        if (relu) {
#pragma unroll
            for (int j = 0; j < 8; ++j) f[j] = fmaxf(f[j], 0.f);
        }
        st8f(C + (size_t)row_g * TN + c0, f);
    }
}

static inline int nblk(long n) { return (int)((n + BLOCK - 1) / BLOCK); }

extern "C" void kernel_launch(void* const* d_in, const int* in_sizes, int n_in,
                              void* d_out, int out_size, void* d_ws, size_t ws_size,
                              hipStream_t stream) {
    const float* x    = (const float*)d_in[0];
    const float* efet = (const float*)d_in[1];
    const int*   src  = (const int*)d_in[2];
    const int*   dst  = (const int*)d_in[3];
    const float* W1 = (const float*)d_in[4];  const float* b1 = (const float*)d_in[5];
    const float* W2 = (const float*)d_in[6];  const float* b2 = (const float*)d_in[7];
    const float* W3 = (const float*)d_in[8];  const float* b3 = (const float*)d_in[9];
    const float* W4 = (const float*)d_in[10]; const float* b4 = (const float*)d_in[11];
    const float* W5 = (const float*)d_in[12]; const float* b5 = (const float*)d_in[13];
    float* out = (float*)d_out;

    const int N = in_sizes[0] / 16;
    const int E = in_sizes[2];
    const int NBUK = (N + 127) / 128;

    // ---- workspace layout (4B units, 16B-aligned chunks) ----
    float* fws = (float*)d_ws;
    size_t o = 0;
    auto alloc = [&](size_t nf) { float* p = fws + o; o += (nf + 3) & ~(size_t)3; return p; };
    float*  normO     = alloc(N);
    float*  normI     = alloc(N);
    int2*   rowSpan   = (int2*)alloc(2 * (size_t)N);
    int2*   edges     = (int2*)alloc(2 * (size_t)E);
    // --- contiguous zeroed region: degO_x, scur, ovcur, gcur ---
    int*    degO_x    = (int*)alloc(8 * (size_t)N);
    int*    scur      = (int*)alloc((size_t)NBUK * PAD);
    int*    ovcur     = (int*)alloc((size_t)NBUK * PAD);
    int*    gcur      = (int*)alloc(4);
    size_t zeroBytes  = (8 * (size_t)N + (size_t)NBUK * PAD + (size_t)NBUK * PAD + 4) * 4;
    int2*   staging   = (int2*)alloc(2 * (size_t)NBUK * SCAP);
    int2*   overflow  = (int2*)alloc(2 * (size_t)NBUK * OVCAP);
    __half* xh        = (__half*)alloc(8 * (size_t)N);
    __half* bufA      = (__half*)alloc(128 * (size_t)N);
    __half* bufB      = (__half*)alloc(128 * (size_t)N);
    __half* bufC      = (__half*)alloc(64 * (size_t)N);
    float*  t5f       = (float*)bufB;                    // layer-5 fp32 temp (m4 lives in bufC)

    // ---- CSR build: binA -> binB (binB also does normO + x->fp16) ----
    (void)hipMemsetAsync(degO_x, 0, zeroBytes, stream);
    binA_kernel<<<BINA_BLOCKS, BINA_THREADS, 0, stream>>>(
        src, dst, efet, degO_x, scur, ovcur, staging, overflow, N, E, NBUK);
    binB_kernel<<<NBUK, 256, 0, stream>>>(scur, ovcur, staging, overflow,
                                          gcur, rowSpan, normI, edges,
                                          degO_x, x, xh, normO, N);

    // ---- Layer 1: agg16 -> GEMM 16->256 (+normI,b1,relu) -> u1 (bufA) ----
    agg8_kernel<16><<<nblk((long)N * 2), BLOCK, 0, stream>>>(
        xh, bufC, rowSpan, edges, 0, nullptr, nullptr, N, 0);
    gemm_tiled<16, 8, 256><<<(N + 63) / 64, 256, 0, stream>>>(
        bufC, W1, nullptr, normI, b1, bufA, N, 16, 1);

    // ---- Layer 2: GEMM u1@W2 256->128 -> q2 (bufB); EWA128 (x normO) -> m2 (bufC);
    //      gc-agg128 (+normI,b2,relu) -> u2 (bufB) ----
    gemm_tiled<32, 8, 128><<<(N + 127) / 128, 256, 0, stream>>>(
        bufA, W2, nullptr, nullptr, nullptr, bufB, N, 256, 0);
    agg8_kernel<128><<<nblk((long)N * 16), BLOCK, 0, stream>>>(
        bufB, bufC, rowSpan, edges, 1, normO, nullptr, N, 0);
    agg8_kernel<128><<<nblk((long)N * 16), BLOCK, 0, stream>>>(
        bufC, bufB, rowSpan, edges, 0, normI, b2, N, 1);          // u2 = bufB

    // ---- Layer 3: GEMM u2@W3 128->64 -> q3 (bufA); EWA64 -> m3 (bufC);
    //      gc-agg64 -> u3 (bufB) ----
    gemm_tiled<32, 4, 64><<<(N + 127) / 128, 256, 0, stream>>>(
        bufB, W3, nullptr, nullptr, nullptr, bufA, N, 128, 0);
    agg8_kernel<64><<<nblk((long)N * 8), BLOCK, 0, stream>>>(
        bufA, bufC, rowSpan, edges, 1, normO, nullptr, N, 0);
    agg8_kernel<64><<<nblk((long)N * 8), BLOCK, 0, stream>>>(
        bufC, bufB, rowSpan, edges, 0, normI, b3, N, 1);          // u3 = bufB

    // ---- Layer 4: GEMM u3@W4 64->32 -> q4 (bufA); EWA32 -> m4 (bufC);
    //      gc32_fused: agg + normI,b4,relu + @W5 + normO -> t5f (bufB as fp32) ----
    gemm_tiled<32, 2, 32><<<(N + 127) / 128, 256, 0, stream>>>(
        bufB, W4, nullptr, nullptr, nullptr, bufA, N, 64, 0);
    agg8_kernel<32><<<nblk((long)N * 4), BLOCK, 0, stream>>>(
        bufA, bufC, rowSpan, edges, 1, normO, nullptr, N, 0);     // m4 = bufC
    gc32_fused<<<nblk((long)N * 4), BLOCK, 0, stream>>>(
        bufC, t5f, rowSpan, edges, normI, b4, normO, W5, N);

    // ---- Layer 5: agg4 -> out ----
    agg4_kernel<<<nblk((long)N), BLOCK, 0, stream>>>(
        t5f, out, rowSpan, edges, normI, b5, N);
}

// Round 10
// 373.210 us; speedup vs baseline: 1.0850x; 1.0850x over previous
//
#include <hip/hip_runtime.h>
#include <hip/hip_fp16.h>

#define BLOCK 256
#define PAD 16        // one counter per 64B cache line
#define SCAP 4096     // unified staging capacity per bucket (records)
#define OVCAP 4096    // overflow capacity per bucket
#define BUFCAP 4352   // binB LDS record capacity

// binA LDS binning
#define NBIN 416          // >= NBUK (=391 for N=50000)
#define CAPBIG 16         // per-bin LDS capacity (records)
#define BINA_THREADS 1024
#define BINA_BLOCKS 256

typedef _Float16 h2v __attribute__((ext_vector_type(2)));
typedef _Float16 h8v __attribute__((ext_vector_type(8)));
typedef float f4v __attribute__((ext_vector_type(4)));

#if defined(__has_builtin) && __has_builtin(__builtin_amdgcn_sched_barrier)
#define SCHED_FENCE() __builtin_amdgcn_sched_barrier(0)
#else
#define SCHED_FENCE()
#endif

// ---------------- helpers ----------------
__device__ inline void st4f(__half* p, float4 v) {
    __half2 a = __floats2half2_rn(v.x, v.y);
    __half2 b = __floats2half2_rn(v.z, v.w);
    uint2 u;
    u.x = *reinterpret_cast<unsigned*>(&a);
    u.y = *reinterpret_cast<unsigned*>(&b);
    *(uint2*)p = u;
}
__device__ inline void st4f(float* p, float4 v) { *(float4*)p = v; }
__device__ inline void st8f(float* p, const float f[8]) {
    *(float4*)p       = make_float4(f[0], f[1], f[2], f[3]);
    *(float4*)(p + 4) = make_float4(f[4], f[5], f[6], f[7]);
}
__device__ inline void st8f(__half* p, const float f[8]) {
    union { __half2 h[4]; float4 v; } u;
    u.h[0] = __floats2half2_rn(f[0], f[1]);
    u.h[1] = __floats2half2_rn(f[2], f[3]);
    u.h[2] = __floats2half2_rn(f[4], f[5]);
    u.h[3] = __floats2half2_rn(f[6], f[7]);
    *(float4*)p = u.v;
}
__device__ inline void ld2v(const __half* p, float* f) {
    float2 v = __half22float2(*(const __half2*)p); f[0] = v.x; f[1] = v.y;
}
__device__ inline void ld4v(const __half* p, float* f) {
    float2 r = *(const float2*)p;   // 8B = 4 halves
    const __half2* h = (const __half2*)&r;
    float2 a = __half22float2(h[0]), b = __half22float2(h[1]);
    f[0] = a.x; f[1] = a.y; f[2] = b.x; f[3] = b.y;
}
__device__ inline void ld8v(const __half* p, float* f) {
    float4 r = *(const float4*)p;
    const __half2* h = (const __half2*)&r;
#pragma unroll
    for (int j = 0; j < 4; ++j) {
        float2 fj = __half22float2(h[j]);
        f[2*j] = fj.x; f[2*j+1] = fj.y;
    }
}
__device__ inline float4 ld4f(const float* p) { return *(const float4*)p; }
__device__ inline float edgeW(int2 er) {
    return __half2float(__ushort_as_half((unsigned short)(er.y & 0xffff)));
}
__device__ inline h2v packh2(float a, float b) {
    h2v r; r.x = (_Float16)a; r.y = (_Float16)b; return r;
}
// non-temporal 8B record load (int2 via long long bit-cast)
__device__ inline int2 ntld2(const int2* p) {
    long long v = __builtin_nontemporal_load((const long long*)p);
    union { long long l; int2 i; } u; u.l = v; return u.i;
}

// ---------------- binA: LDS-binned edge staging, full-line flushes ----------------
__global__ __launch_bounds__(BINA_THREADS) void binA_kernel(
    const int* __restrict__ src, const int* __restrict__ dst,
    const float* __restrict__ efet,
    int* __restrict__ degO_x,
    int* __restrict__ scur, int* __restrict__ ovcur,
    int2* __restrict__ staging, int2* __restrict__ overflow,
    int N, int E, int NBUK) {
    __shared__ int2 bins[NBIN][CAPBIG];
    __shared__ int  lcnt[NBIN];
    const int t = threadIdx.x;
    for (int b = t; b < NBIN; b += BINA_THREADS) lcnt[b] = 0;
    __syncthreads();

    const int nbuk_c = (NBUK < NBIN) ? NBUK : NBIN;
    const int chunk = (E + gridDim.x - 1) / gridDim.x;
    const int e0 = blockIdx.x * chunk;
    int e1 = e0 + chunk; if (e1 > E) e1 = E;
    const int xcc = __builtin_amdgcn_s_getreg(63508) & 7;   // hwreg(XCC_ID)

    for (int base = e0; base < e1; base += BINA_THREADS) {
        const int e = base + t;
        if (e < e1) {
            int s = __builtin_nontemporal_load(src + e);
            int d = __builtin_nontemporal_load(dst + e);
            float w = __builtin_nontemporal_load(efet + e);
            atomicAdd(&degO_x[(size_t)xcc * N + s], 1);     // XCD-local, fire & forget
            int b = d >> 7;
            int2 rec;
            rec.x = s;
            rec.y = (int)__half_as_ushort(__float2half(w)) | ((d & 127) << 16);
            int pos = (b < NBIN) ? atomicAdd(&lcnt[b], 1) : CAPBIG;
            if (pos < CAPBIG) {
                bins[b][pos] = rec;
            } else {
                int q = atomicAdd(&ovcur[b * PAD], 1);
                if (q < OVCAP) overflow[(size_t)b * OVCAP + q] = rec;
            }
        }
        __syncthreads();
        // flush full groups of 8 records (64B-aligned line writes)
        for (int b = t; b < nbuk_c; b += BINA_THREADS) {
            int c = lcnt[b];
            if (c > CAPBIG) c = CAPBIG;
            int nf = c & ~7;
            if (nf) {
                int g = atomicAdd(&scur[b * PAD], nf);
                if (g + nf <= SCAP) {
                    const int4* s4 = (const int4*)&bins[b][0];
                    int4* d4 = (int4*)(staging + (size_t)b * SCAP + g);
                    for (int i = 0; i < (nf >> 1); ++i) d4[i] = s4[i];
                } else {
                    for (int i = 0; i < nf; ++i) {
                        int gg = g + i;
                        if (gg < SCAP) staging[(size_t)b * SCAP + gg] = bins[b][i];
                        else {
                            int q = atomicAdd(&ovcur[b * PAD], 1);
                            if (q < OVCAP) overflow[(size_t)b * OVCAP + q] = bins[b][i];
                        }
                    }
                }
                int rem = c - nf;
                for (int i = 0; i < rem; ++i) bins[b][i] = bins[b][nf + i];
                lcnt[b] = rem;
            }
        }
        __syncthreads();
    }
    for (int b = t; b < nbuk_c; b += BINA_THREADS) {
        int c = lcnt[b];
        if (c > CAPBIG) c = CAPBIG;
        if (c > 0) {
            int q = atomicAdd(&ovcur[b * PAD], c);
            for (int i = 0; i < c; ++i)
                if (q + i < OVCAP) overflow[(size_t)b * OVCAP + q + i] = bins[b][i];
        }
    }
}

// ---------------- binB: bucket drain -> rowSpan + edges + norms + xh ----------------
__global__ __launch_bounds__(256) void binB_kernel(
    const int* __restrict__ scur, const int* __restrict__ ovcur,
    const int2* __restrict__ staging, const int2* __restrict__ overflow,
    int* __restrict__ gcur, int2* __restrict__ rowSpan, float* __restrict__ normI,
    int2* __restrict__ edges,
    const int* __restrict__ degO_x, const float* __restrict__ x,
    __half* __restrict__ xh, float* __restrict__ normO, int N) {
    __shared__ int2 buf[BUFCAP];
    __shared__ int cnt[128];
    __shared__ int rs[128];
    __shared__ int cur[128];
    __shared__ float nO[128];
    __shared__ int base;
    int b = blockIdx.x;
    int v0 = b << 7;
    int t = threadIdx.x;
    int nn = N - v0; if (nn > 128) nn = 128;
    if (t < 128) cnt[t] = 0;

    int c = scur[b * PAD];
    if (c > SCAP) c = SCAP;
    int oc = ovcur[b * PAD];
    if (oc > OVCAP) oc = OVCAP;
    int total = c + oc;
    if (total > BUFCAP) total = BUFCAP;
    __syncthreads();

    {
        const int2* reg = staging + (size_t)b * SCAP;
        for (int i = t; i < c; i += 256) {
            if (i < BUFCAP) buf[i] = ntld2(reg + i);
        }
    }
    {
        const int2* reg = overflow + (size_t)b * OVCAP;
        for (int i = t; i < oc; i += 256) {
            int o = c + i;
            if (o < BUFCAP) buf[o] = ntld2(reg + i);
        }
    }
    __syncthreads();

    for (int i = t; i < total; i += 256)
        atomicAdd(&cnt[(buf[i].y >> 16) & 127], 1);
    __syncthreads();

    if (t == 0) {
        base = atomicAdd(gcur, total);
        int a2 = 0;
        for (int k = 0; k < 128; ++k) { rs[k] = a2; a2 += cnt[k]; }
    }
    __syncthreads();

    if (t < 128) {
        cur[t] = 0;
        int v = v0 + t;
        if (v < N) {
            int2 sp;
            sp.x = base + rs[t];
            sp.y = sp.x + cnt[t];
            rowSpan[v] = sp;
            normI[v] = rsqrtf(fmaxf((float)cnt[t], 1.0f));
            int dsum = 0;
#pragma unroll
            for (int k = 0; k < 8; ++k) dsum += degO_x[(size_t)k * N + v];
            float wv = rsqrtf(fmaxf((float)dsum, 1.0f));
            nO[t] = wv;
            normO[v] = wv;
        }
    }
    __syncthreads();

    for (int i = t; i < total; i += 256) {
        int2 rec = buf[i];
        int dl = (rec.y >> 16) & 127;
        int lp = atomicAdd(&cur[dl], 1);
        edges[base + rs[dl] + lp] = rec;
    }

    for (int i = t; i < nn * 4; i += 256) {
        int vl = i >> 2, cc = (i & 3) * 4;
        int v = v0 + vl;
        float4 f = ld4f(x + (size_t)v * 16 + cc);
        float wv = nO[vl];
        f.x *= wv; f.y *= wv; f.z *= wv; f.w *= wv;
        st4f(xh + (size_t)v * 16 + cc, f);
    }
}

// ---------------- CSR gather-agg, 8 cols/thread, LDS-staged edge window ------------
template <int D>
__global__ __launch_bounds__(256) void agg8_kernel(
    const __half* __restrict__ in, __half* __restrict__ out,
    const int2* __restrict__ rowSpan, const int2* __restrict__ edges,
    int useW,
    const float* __restrict__ dstScale,   // null -> skip scale+bias
    const float* __restrict__ bias,       // null -> scale only
    int N, int relu) {
    constexpr int TPN = D / 8;
    constexpr int NN  = 256 / TPN;                       // nodes per block
    constexpr int ECAP = (NN * 32 < 2560) ? NN * 32 : 2560;  // >=11 sd over mean NN*16
    __shared__ int2 eb[ECAP];
    __shared__ int s_w[2];
    const int t = threadIdx.x;
    const int v0 = blockIdx.x * NN;
    if (t == 0) {
        int vl = v0 + NN - 1; if (vl >= N) vl = N - 1;
        s_w[0] = rowSpan[v0].x;
        s_w[1] = rowSpan[vl].y;
    }
    __syncthreads();
    const int wbeg = s_w[0];
    int nst = s_w[1] - wbeg; if (nst > ECAP) nst = ECAP;
    for (int i = t; i < nst; i += 256) eb[i] = ntld2(&edges[wbeg + i]);
    __syncthreads();

    int v = v0 + t / TPN;
    int c8 = (t % TPN) * 8;
    if (v >= N) return;
    int2 sp = rowSpan[v];
    int beg = sp.x, end = sp.y;
    float a[8];
#pragma unroll
    for (int k = 0; k < 8; ++k) a[k] = 0.f;
    const __half* base = in + c8;

    auto erec = [&](int j) -> int2 {
        int o = j - wbeg;
        return (o < nst) ? eb[o] : edges[j];
    };

    int j = beg;
    for (; j + 8 <= end; j += 8) {
        int2 er[8];
#pragma unroll
        for (int q = 0; q < 8; ++q) er[q] = erec(j + q);
        SCHED_FENCE();
        float4 raw[8];
#pragma unroll
        for (int q = 0; q < 8; ++q) raw[q] = *(const float4*)(base + (size_t)er[q].x * D);
        SCHED_FENCE();
#pragma unroll
        for (int q = 0; q < 8; ++q) {
            float w = useW ? edgeW(er[q]) : 1.f;
            const __half2* h = (const __half2*)&raw[q];
#pragma unroll
            for (int p = 0; p < 4; ++p) {
                float2 fj = __half22float2(h[p]);
                a[2*p]   += fj.x * w;
                a[2*p+1] += fj.y * w;
            }
        }
    }
    if (j + 4 <= end) {
        int2 er[4];
#pragma unroll
        for (int q = 0; q < 4; ++q) er[q] = erec(j + q);
        SCHED_FENCE();
        float4 raw[4];
#pragma unroll
        for (int q = 0; q < 4; ++q) raw[q] = *(const float4*)(base + (size_t)er[q].x * D);
        SCHED_FENCE();
#pragma unroll
        for (int q = 0; q < 4; ++q) {
            float w = useW ? edgeW(er[q]) : 1.f;
            const __half2* h = (const __half2*)&raw[q];
#pragma unroll
            for (int p = 0; p < 4; ++p) {
                float2 fj = __half22float2(h[p]);
                a[2*p]   += fj.x * w;
                a[2*p+1] += fj.y * w;
            }
        }
        j += 4;
    }
    for (; j < end; ++j) {
        int2 er = erec(j);
        float w = useW ? edgeW(er) : 1.f;
        float xv[8];
        ld8v(base + (size_t)er.x * D, xv);
#pragma unroll
        for (int k = 0; k < 8; ++k) a[k] += xv[k] * w;
    }
    if (dstScale) {
        float sc = dstScale[v];
        if (bias) {
#pragma unroll
            for (int k = 0; k < 8; ++k) a[k] = a[k] * sc + bias[c8 + k];
        } else {
#pragma unroll
            for (int k = 0; k < 8; ++k) a[k] *= sc;
        }
    }
    if (relu) {
#pragma unroll
        for (int k = 0; k < 8; ++k) a[k] = fmaxf(a[k], 0.f);
    }
    st8f(out + (size_t)v * D + c8, a);
}

// ---------------- gc32 fused with 32->4 GEMM (W5), LDS-staged edges ----------------
__global__ __launch_bounds__(256) void gc32_fused(
    const __half* __restrict__ in, float* __restrict__ t5,
    const int2* __restrict__ rowSpan, const int2* __restrict__ edges,
    const float* __restrict__ normI, const float* __restrict__ b4,
    const float* __restrict__ normO, const float* __restrict__ W5,
    int N) {
    constexpr int NN = 64;               // nodes per block (4 threads/node)
    constexpr int ECAP = 2048;
    __shared__ int2 eb[ECAP];
    __shared__ int s_w[2];
    const int t = threadIdx.x;
    const int v0 = blockIdx.x * NN;
    if (t == 0) {
        int vl = v0 + NN - 1; if (vl >= N) vl = N - 1;
        s_w[0] = rowSpan[v0].x;
        s_w[1] = rowSpan[vl].y;
    }
    __syncthreads();
    const int wbeg = s_w[0];
    int nst = s_w[1] - wbeg; if (nst > ECAP) nst = ECAP;
    for (int i = t; i < nst; i += 256) eb[i] = ntld2(&edges[wbeg + i]);
    __syncthreads();

    int v = v0 + (t >> 2);
    int q = t & 3;
    int c8 = q * 8;
    if (v >= N) return;
    int2 sp = rowSpan[v];
    int beg = sp.x, end = sp.y;
    float a[8];
#pragma unroll
    for (int k = 0; k < 8; ++k) a[k] = 0.f;
    const __half* base = in + c8;

    auto erec = [&](int j) -> int2 {
        int o = j - wbeg;
        return (o < nst) ? eb[o] : edges[j];
    };

    int j = beg;
    for (; j + 8 <= end; j += 8) {
        int2 er[8];
#pragma unroll
        for (int p = 0; p < 8; ++p) er[p] = erec(j + p);
        SCHED_FENCE();
        float4 raw[8];
#pragma unroll
        for (int p = 0; p < 8; ++p) raw[p] = *(const float4*)(base + (size_t)er[p].x * 32);
        SCHED_FENCE();
#pragma unroll
        for (int p = 0; p < 8; ++p) {
            const __half2* h = (const __half2*)&raw[p];
#pragma unroll
            for (int s = 0; s < 4; ++s) {
                float2 fj = __half22float2(h[s]);
                a[2*s]   += fj.x;
                a[2*s+1] += fj.y;
            }
        }
    }
    for (; j < end; ++j) {
        int2 er = erec(j);
        float xv[8];
        ld8v(base + (size_t)er.x * 32, xv);
#pragma unroll
        for (int k = 0; k < 8; ++k) a[k] += xv[k];
    }
    float sc = normI[v];
#pragma unroll
    for (int k = 0; k < 8; ++k) a[k] = fmaxf(a[k] * sc + b4[c8 + k], 0.f);

    float p4[4] = {0.f, 0.f, 0.f, 0.f};
#pragma unroll
    for (int k = 0; k < 8; ++k) {
        float4 wr = ld4f(W5 + (size_t)(c8 + k) * 4);
        p4[0] += a[k] * wr.x; p4[1] += a[k] * wr.y;
        p4[2] += a[k] * wr.z; p4[3] += a[k] * wr.w;
    }
#pragma unroll
    for (int c = 0; c < 4; ++c) {
        p4[c] += __shfl_xor(p4[c], 1);
        p4[c] += __shfl_xor(p4[c], 2);
    }
    if (q == 0) {
        float no = normO[v];
        st4f(t5 + (size_t)v * 4, make_float4(p4[0]*no, p4[1]*no, p4[2]*no, p4[3]*no));
    }
}

// ---------------- final agg: D=4, fp32, batched loads ----------------
__global__ void agg4_kernel(const float* __restrict__ in, float* __restrict__ out,
                            const int2* __restrict__ rowSpan, const int2* __restrict__ edges,
                            const float* __restrict__ dstScale, const float* __restrict__ bias,
                            int N) {
    int v = blockIdx.x * blockDim.x + threadIdx.x;
    if (v >= N) return;
    int2 sp = rowSpan[v];
    int beg = sp.x, end = sp.y;
    float ax = 0.f, ay = 0.f, az = 0.f, aw = 0.f;
    int j = beg;
    for (; j + 4 <= end; j += 4) {
        int2 er[4];
#pragma unroll
        for (int q = 0; q < 4; ++q) er[q] = edges[j + q];
        SCHED_FENCE();
        float4 raw[4];
#pragma unroll
        for (int q = 0; q < 4; ++q) raw[q] = ld4f(in + (size_t)er[q].x * 4);
        SCHED_FENCE();
#pragma unroll
        for (int q = 0; q < 4; ++q) {
            ax += raw[q].x; ay += raw[q].y; az += raw[q].z; aw += raw[q].w;
        }
    }
    for (; j < end; ++j) {
        float4 val = ld4f(in + (size_t)edges[j].x * 4);
        ax += val.x; ay += val.y; az += val.z; aw += val.w;
    }
    float sc = dstScale[v];
    ax = ax * sc + bias[0];
    ay = ay * sc + bias[1];
    az = az * sc + bias[2];
    aw = aw * sc + bias[3];
    st4f(out + (size_t)v * 4, make_float4(ax, ay, az, aw));
}

// ---------------- MFMA GEMM: M x K1 (fp16, row-major) @ K1 x TN (fp32) -> fp16 -----
// Round-10: fdot2 GEMMs were 5x off their VALU floor (50us vs 10us, MfmaUtil=0).
// v_mfma_f32_16x16x32_f16 does 16384 FLOP/wave-inst vs fdot2's 256. 64 rows/block,
// 4 waves (wave w owns rows 16w..16w+15). A and W staged FRAGMENT-MAJOR in LDS so
// each lane's 8-half fragment is one contiguous 16B read (conflict-free by
// construction). Fragment layouts (AMD matrix-core mapping, harness-verified via
// random asymmetric W): A[l&15][(l>>4)*8+j]; B[(l>>4)*8+j][l&15];
// C/D: col=lane&15, row=(lane>>4)*4+reg.
template <int TN, int K1>
__global__ __launch_bounds__(256) void gemm_mfma(
    const __half* __restrict__ A, const float* __restrict__ W,
    __half* __restrict__ C, int N)
{
    constexpr int NCT = TN / 16;        // 16-col output tiles
    constexpr int NKS = K1 / 32;        // K-steps
    __shared__ _Float16 Alds[4][64][8]; // [wave][lane][j]
    __shared__ _Float16 Blds[NCT][64][8];

    const int t    = threadIdx.x;
    const int w    = t >> 6;
    const int lane = t & 63;
    const int row0 = blockIdx.x * 64;

    f4v acc[NCT];
#pragma unroll
    for (int ct = 0; ct < NCT; ++ct)
#pragma unroll
        for (int r = 0; r < 4; ++r) acc[ct][r] = 0.f;

    const int srow   = t >> 2;          // staging row 0..63
    const int sq     = t & 3;           // k-quarter (8 halves each)
    const int grow_s = row0 + srow;

    for (int ks = 0; ks < NKS; ++ks) {
        const int k0 = ks * 32;
        // ---- stage A fragment-major: Alds[w][l][j] = A[16w+(l&15)][k0+(l>>4)*8+j]
        {
            h8v av;
#pragma unroll
            for (int jj = 0; jj < 8; ++jj) av[jj] = (_Float16)0;
            if (grow_s < N)
                av = *(const h8v*)(A + (size_t)grow_s * K1 + k0 + sq * 8);
            *(h8v*)&Alds[srow >> 4][(sq << 4) | (srow & 15)][0] = av;
        }
        // ---- stage B fragment-major (fp32 W -> fp16), k-pairs for 4B LDS writes
        for (int idx = t; idx < 16 * TN; idx += 256) {
            int k2 = idx / TN;          // 0..15 -> k = 2*k2
            int c  = idx % TN;
            int k  = k2 << 1;
            h2v hv = packh2(W[(size_t)(k0 + k) * TN + c],
                            W[(size_t)(k0 + k + 1) * TN + c]);
            *(h2v*)&Blds[c >> 4][((k >> 3) << 4) | (c & 15)][k & 7] = hv;
        }
        __syncthreads();
        h8v af = *(const h8v*)&Alds[w][lane][0];
#pragma unroll
        for (int ct = 0; ct < NCT; ++ct) {
            h8v bf = *(const h8v*)&Blds[ct][lane][0];
            acc[ct] = __builtin_amdgcn_mfma_f32_16x16x32_f16(af, bf, acc[ct], 0, 0, 0);
        }
        __syncthreads();
    }

    // ---- epilogue: lane holds C[(l>>4)*4+r][ct*16+(l&15)] of the wave's 16x16 tile
    const int lr = (lane >> 4) << 2;
    const int lc = lane & 15;
#pragma unroll
    for (int ct = 0; ct < NCT; ++ct) {
#pragma unroll
        for (int r = 0; r < 4; ++r) {
            int grow = row0 + (w << 4) + lr + r;
            if (grow < N)
                C[(size_t)grow * TN + ct * 16 + lc] = __float2half(acc[ct][r]);
        }
    }
}

// ---------------- tiled GEMM with v_dot2_f32_f16 (kept for the K=16 layer-1) ------
template <int KT, int RPT, int TN>
__global__ __launch_bounds__(256) void gemm_tiled(
    const __half* __restrict__ A, const float* __restrict__ W,
    const float* __restrict__ rowScaleIn,   // null -> 1
    const float* __restrict__ rowScaleOut,  // null -> no scale/bias
    const float* __restrict__ bias,
    __half* __restrict__ C, int N, int K1, int relu)
{
    constexpr int NC8 = TN / 8;
    constexpr int RT  = 256 / NC8;
    constexpr int TM  = RT * RPT;
    constexpr int AFPT = TM * KT / 256;
    constexpr int KP  = KT / 2;
    constexpr int WRS = TN + (TN >> 5) * 4;   // swizzled Wlds row stride (h2v units)
    static_assert(AFPT == 2 || AFPT == 4 || AFPT == 8 || AFPT == 16, "unexpected AFPT");

    __shared__ h2v Alds[KP][TM];
    __shared__ h2v Wlds[KP][WRS];

    const int t    = threadIdx.x;
    const int cg   = t % NC8;
    const int rt   = t / NC8;
    const int c0   = cg * 8;
    const int row0 = blockIdx.x * TM;
    const int pc0  = c0 + ((c0 >> 5) << 2);   // swizzled read base

    const int arow   = t % TM;
    const int akb    = (t / TM) * AFPT;
    const int arow_g = row0 + arow;
    float rsc = 1.0f;
    if (rowScaleIn && arow_g < N) rsc = rowScaleIn[arow_g];

    float acc[RPT][8];
#pragma unroll
    for (int r = 0; r < RPT; ++r)
#pragma unroll
        for (int j = 0; j < 8; ++j) acc[r][j] = 0.f;

    for (int k0 = 0; k0 < K1; k0 += KT) {
        float av[AFPT];
        if (arow_g < N) {
            const __half* ag = A + (size_t)arow_g * K1 + k0 + akb;
            if constexpr (AFPT == 16) { ld8v(ag, av); ld8v(ag + 8, av + 8); }
            else if constexpr (AFPT == 8) ld8v(ag, av);
            else if constexpr (AFPT == 4) ld4v(ag, av);
            else                          ld2v(ag, av);
        } else {
#pragma unroll
            for (int j = 0; j < AFPT; ++j) av[j] = 0.f;
        }
#pragma unroll
        for (int j = 0; j < AFPT; j += 2)
            Alds[(akb + j) >> 1][arow] = packh2(av[j] * rsc, av[j + 1] * rsc);

        for (int i = t; i < KP * TN; i += 256) {
            int kp = i / TN, c = i % TN;
            Wlds[kp][c + ((c >> 5) << 2)] = packh2(W[(size_t)(k0 + 2 * kp) * TN + c],
                                                   W[(size_t)(k0 + 2 * kp + 1) * TN + c]);
        }
        __syncthreads();

#pragma unroll
        for (int kp = 0; kp < KP; ++kp) {
            h2v a2[RPT];
            if constexpr (RPT == 4) {
                union { float4 f; h2v h[4]; } u;
                u.f = *(const float4*)&Alds[kp][rt * 4];
                a2[0] = u.h[0]; a2[1] = u.h[1]; a2[2] = u.h[2]; a2[3] = u.h[3];
            } else if constexpr (RPT == 2) {
                union { float2 f; h2v h[2]; } u;
                u.f = *(const float2*)&Alds[kp][rt * 2];
                a2[0] = u.h[0]; a2[1] = u.h[1];
            } else {
                a2[0] = Alds[kp][rt];
            }
            union { float4 f; h2v h[4]; } w0, w1;
            w0.f = *(const float4*)&Wlds[kp][pc0];
            w1.f = *(const float4*)&Wlds[kp][pc0 + 4];
#pragma unroll
            for (int r = 0; r < RPT; ++r) {
                acc[r][0] = __builtin_amdgcn_fdot2(a2[r], w0.h[0], acc[r][0], false);
                acc[r][1] = __builtin_amdgcn_fdot2(a2[r], w0.h[1], acc[r][1], false);
                acc[r][2] = __builtin_amdgcn_fdot2(a2[r], w0.h[2], acc[r][2], false);
                acc[r][3] = __builtin_amdgcn_fdot2(a2[r], w0.h[3], acc[r][3], false);
                acc[r][4] = __builtin_amdgcn_fdot2(a2[r], w1.h[0], acc[r][4], false);
                acc[r][5] = __builtin_amdgcn_fdot2(a2[r], w1.h[1], acc[r][5], false);
                acc[r][6] = __builtin_amdgcn_fdot2(a2[r], w1.h[2], acc[r][6], false);
                acc[r][7] = __builtin_amdgcn_fdot2(a2[r], w1.h[3], acc[r][7], false);
            }
        }
        __syncthreads();
    }

#pragma unroll
    for (int r = 0; r < RPT; ++r) {
        int row_g = row0 + rt * RPT + r;
        if (row_g >= N) continue;
        float f[8];
        if (rowScaleOut) {
            float sc = rowScaleOut[row_g];
#pragma unroll
            for (int j = 0; j < 8; ++j) f[j] = acc[r][j] * sc + bias[c0 + j];
        } else {
#pragma unroll
            for (int j = 0; j < 8; ++j) f[j] = acc[r][j];
        }
        if (relu) {
#pragma unroll
            for (int j = 0; j < 8; ++j) f[j] = fmaxf(f[j], 0.f);
        }
        st8f(C + (size_t)row_g * TN + c0, f);
    }
}

static inline int nblk(long n) { return (int)((n + BLOCK - 1) / BLOCK); }

extern "C" void kernel_launch(void* const* d_in, const int* in_sizes, int n_in,
                              void* d_out, int out_size, void* d_ws, size_t ws_size,
                              hipStream_t stream) {
    const float* x    = (const float*)d_in[0];
    const float* efet = (const float*)d_in[1];
    const int*   src  = (const int*)d_in[2];
    const int*   dst  = (const int*)d_in[3];
    const float* W1 = (const float*)d_in[4];  const float* b1 = (const float*)d_in[5];
    const float* W2 = (const float*)d_in[6];  const float* b2 = (const float*)d_in[7];
    const float* W3 = (const float*)d_in[8];  const float* b3 = (const float*)d_in[9];
    const float* W4 = (const float*)d_in[10]; const float* b4 = (const float*)d_in[11];
    const float* W5 = (const float*)d_in[12]; const float* b5 = (const float*)d_in[13];
    float* out = (float*)d_out;

    const int N = in_sizes[0] / 16;
    const int E = in_sizes[2];
    const int NBUK = (N + 127) / 128;
    const int NB64 = (N + 63) / 64;

    // ---- workspace layout (4B units, 16B-aligned chunks) ----
    float* fws = (float*)d_ws;
    size_t o = 0;
    auto alloc = [&](size_t nf) { float* p = fws + o; o += (nf + 3) & ~(size_t)3; return p; };
    float*  normO     = alloc(N);
    float*  normI     = alloc(N);
    int2*   rowSpan   = (int2*)alloc(2 * (size_t)N);
    int2*   edges     = (int2*)alloc(2 * (size_t)E);
    // --- contiguous zeroed region: degO_x, scur, ovcur, gcur ---
    int*    degO_x    = (int*)alloc(8 * (size_t)N);
    int*    scur      = (int*)alloc((size_t)NBUK * PAD);
    int*    ovcur     = (int*)alloc((size_t)NBUK * PAD);
    int*    gcur      = (int*)alloc(4);
    size_t zeroBytes  = (8 * (size_t)N + (size_t)NBUK * PAD + (size_t)NBUK * PAD + 4) * 4;
    int2*   staging   = (int2*)alloc(2 * (size_t)NBUK * SCAP);
    int2*   overflow  = (int2*)alloc(2 * (size_t)NBUK * OVCAP);
    __half* xh        = (__half*)alloc(8 * (size_t)N);
    __half* bufA      = (__half*)alloc(128 * (size_t)N);
    __half* bufB      = (__half*)alloc(128 * (size_t)N);
    __half* bufC      = (__half*)alloc(64 * (size_t)N);
    float*  t5f       = (float*)bufB;                    // layer-5 fp32 temp (m4 lives in bufC)

    // ---- CSR build: binA -> binB (binB also does normO + x->fp16) ----
    (void)hipMemsetAsync(degO_x, 0, zeroBytes, stream);
    binA_kernel<<<BINA_BLOCKS, BINA_THREADS, 0, stream>>>(
        src, dst, efet, degO_x, scur, ovcur, staging, overflow, N, E, NBUK);
    binB_kernel<<<NBUK, 256, 0, stream>>>(scur, ovcur, staging, overflow,
                                          gcur, rowSpan, normI, edges,
                                          degO_x, x, xh, normO, N);

    // ---- Layer 1: agg16 -> GEMM 16->256 (+normI,b1,relu) -> u1 (bufA) ----
    agg8_kernel<16><<<nblk((long)N * 2), BLOCK, 0, stream>>>(
        xh, bufC, rowSpan, edges, 0, nullptr, nullptr, N, 0);
    gemm_tiled<16, 4, 256><<<(N + 31) / 32, 256, 0, stream>>>(
        bufC, W1, nullptr, normI, b1, bufA, N, 16, 1);

    // ---- Layer 2: MFMA GEMM u1@W2 256->128 -> q2 (bufB); EWA128 -> m2 (bufC);
    //      gc-agg128 (+normI,b2,relu) -> u2 (bufB) ----
    gemm_mfma<128, 256><<<NB64, 256, 0, stream>>>(bufA, W2, bufB, N);
    agg8_kernel<128><<<nblk((long)N * 16), BLOCK, 0, stream>>>(
        bufB, bufC, rowSpan, edges, 1, normO, nullptr, N, 0);
    agg8_kernel<128><<<nblk((long)N * 16), BLOCK, 0, stream>>>(
        bufC, bufB, rowSpan, edges, 0, normI, b2, N, 1);          // u2 = bufB

    // ---- Layer 3: MFMA GEMM u2@W3 128->64 -> q3 (bufA); EWA64 -> m3 (bufC);
    //      gc-agg64 -> u3 (bufB) ----
    gemm_mfma<64, 128><<<NB64, 256, 0, stream>>>(bufB, W3, bufA, N);
    agg8_kernel<64><<<nblk((long)N * 8), BLOCK, 0, stream>>>(
        bufA, bufC, rowSpan, edges, 1, normO, nullptr, N, 0);
    agg8_kernel<64><<<nblk((long)N * 8), BLOCK, 0, stream>>>(
        bufC, bufB, rowSpan, edges, 0, normI, b3, N, 1);          // u3 = bufB

    // ---- Layer 4: MFMA GEMM u3@W4 64->32 -> q4 (bufA); EWA32 -> m4 (bufC);
    //      gc32_fused: agg + normI,b4,relu + @W5 + normO -> t5f ----
    gemm_mfma<32, 64><<<NB64, 256, 0, stream>>>(bufB, W4, bufA, N);
    agg8_kernel<32><<<nblk((long)N * 4), BLOCK, 0, stream>>>(
        bufA, bufC, rowSpan, edges, 1, normO, nullptr, N, 0);     // m4 = bufC
    gc32_fused<<<nblk((long)N * 4), BLOCK, 0, stream>>>(
        bufC, t5f, rowSpan, edges, normI, b4, normO, W5, N);

    // ---- Layer 5: agg4 -> out ----
    agg4_kernel<<<nblk((long)N), BLOCK, 0, stream>>>(
        t5f, out, rowSpan, edges, normI, b5, N);
}